// Round 9
// baseline (131.441 us; speedup 1.0000x reference)
//
#include <hip/hip_runtime.h>
#include <hip/hip_cooperative_groups.h>

namespace cg = cooperative_groups;

#define EPS 1e-5f
#define TPB 256

// Math: theta_p = mean(x[b,0,6p:6p+6,0:6]); c_p = cos(theta_p);
// CNOT chain (0,1)(1,2)(2,3)(3,0) is a classical XOR map =>
// z0=c1*c2*c3, z1=c0*c1, z2=c0*c1*c2, z3=c0*c1*c2*c3; then batchnorm over B.
//
// Cooperative single-kernel path (grid sized via occupancy query, verified fit):
//   Phase A: round-7 proven inner body (dense [0,2688) reads, packed-halving
//            butterfly), z -> LDS, per-block partials -> global table.
//   grid.sync()
//   Phase B: every block redundantly reduces the nblk x 8 table (L2-resident).
//   Phase C: normalize from LDS, write out.
// Fallback (coop rejected): round-7 two-kernel path.
//
// ws layout:
//   coop:     [0, nblk*32)                float partials[nblk][8]
//   fallback: [0, bsz*16) z ; [bsz*16, +NB*32) partials

__device__ __forceinline__ void qnat_pair(const float* __restrict__ x, int bsz,
                                          int imgA, int imgB, int lane,
                                          int j1, int j2, int m0, int p0, int m1, int p1,
                                          int m2, int p2, bool b0, bool b1, int k,
                                          float& zA, float& zB) {
    float4 vA0 = make_float4(0.f,0.f,0.f,0.f), vA1 = vA0, vA2 = vA0;
    float4 vB0 = vA0, vB1 = vA0, vB2 = vA0;
    if (imgA < bsz) {
        const float* ipA = x + (size_t)imgA * 784;
        vA0 = *reinterpret_cast<const float4*>(ipA + 4 * lane);
        vA1 = *reinterpret_cast<const float4*>(ipA + 4 * j1);
        if (lane < 40) vA2 = *reinterpret_cast<const float4*>(ipA + 4 * j2);
    }
    if (imgB < bsz) {
        const float* ipB = x + (size_t)imgB * 784;
        vB0 = *reinterpret_cast<const float4*>(ipB + 4 * lane);
        vB1 = *reinterpret_cast<const float4*>(ipB + 4 * j1);
        if (lane < 40) vB2 = *reinterpret_cast<const float4*>(ipB + 4 * j2);
    }

    float aA0 = 0.f, aA1 = 0.f, aA2 = 0.f, aA3 = 0.f;
    float aB0 = 0.f, aB1 = 0.f, aB2 = 0.f, aB3 = 0.f;
    {
        float h2 = vA0.x + vA0.y, h4 = h2 + vA0.z + vA0.w;
        float c  = (m0 == 0) ? h4 : ((m0 == 1) ? h2 : 0.f);
        aA0 += (p0 == 0) ? c : 0.f; aA1 += (p0 == 1) ? c : 0.f;
        aA2 += (p0 == 2) ? c : 0.f; aA3 += (p0 == 3) ? c : 0.f;
        h2 = vB0.x + vB0.y; h4 = h2 + vB0.z + vB0.w;
        c  = (m0 == 0) ? h4 : ((m0 == 1) ? h2 : 0.f);
        aB0 += (p0 == 0) ? c : 0.f; aB1 += (p0 == 1) ? c : 0.f;
        aB2 += (p0 == 2) ? c : 0.f; aB3 += (p0 == 3) ? c : 0.f;

        h2 = vA1.x + vA1.y; h4 = h2 + vA1.z + vA1.w;
        c  = (m1 == 0) ? h4 : ((m1 == 1) ? h2 : 0.f);
        aA0 += (p1 == 0) ? c : 0.f; aA1 += (p1 == 1) ? c : 0.f;
        aA2 += (p1 == 2) ? c : 0.f; aA3 += (p1 == 3) ? c : 0.f;
        h2 = vB1.x + vB1.y; h4 = h2 + vB1.z + vB1.w;
        c  = (m1 == 0) ? h4 : ((m1 == 1) ? h2 : 0.f);
        aB0 += (p1 == 0) ? c : 0.f; aB1 += (p1 == 1) ? c : 0.f;
        aB2 += (p1 == 2) ? c : 0.f; aB3 += (p1 == 3) ? c : 0.f;

        h2 = vA2.x + vA2.y; h4 = h2 + vA2.z + vA2.w;
        c  = (m2 == 0) ? h4 : ((m2 == 1) ? h2 : 0.f);
        aA0 += (p2 == 0) ? c : 0.f; aA1 += (p2 == 1) ? c : 0.f;
        aA2 += (p2 == 2) ? c : 0.f; aA3 += (p2 == 3) ? c : 0.f;
        h2 = vB2.x + vB2.y; h4 = h2 + vB2.z + vB2.w;
        c  = (m2 == 0) ? h4 : ((m2 == 1) ? h2 : 0.f);
        aB0 += (p2 == 0) ? c : 0.f; aB1 += (p2 == 1) ? c : 0.f;
        aB2 += (p2 == 2) ? c : 0.f; aB3 += (p2 == 3) ? c : 0.f;
    }

    // packed-halving butterfly (A and B interleaved)
    float rA = __shfl_xor(b0 ? aA0 : aA1, 1, 64);
    float rB = __shfl_xor(b0 ? aB0 : aB1, 1, 64);
    float uA = (b0 ? aA1 : aA0) + rA;
    float uB = (b0 ? aB1 : aB0) + rB;
    rA = __shfl_xor(b0 ? aA2 : aA3, 1, 64);
    rB = __shfl_xor(b0 ? aB2 : aB3, 1, 64);
    float vA = (b0 ? aA3 : aA2) + rA;
    float vB = (b0 ? aB3 : aB2) + rB;
    rA = __shfl_xor(b1 ? uA : vA, 2, 64);
    rB = __shfl_xor(b1 ? uB : vB, 2, 64);
    float wA = (b1 ? vA : uA) + rA;
    float wB = (b1 ? vB : uB) + rB;
    #pragma unroll
    for (int off = 4; off < 64; off <<= 1) {
        wA += __shfl_xor(wA, off, 64);
        wB += __shfl_xor(wB, off, 64);
    }

    const float kk = 1.0f / 36.0f;
    const float cA = __cosf(wA * kk);      // lane holds c_{lane&3}
    const float cB = __cosf(wB * kk);
    const float cm1A = __shfl_xor(cA, 1, 64);
    const float cm1B = __shfl_xor(cB, 1, 64);
    const float cm2A = __shfl_xor(cA, 2, 64);
    const float cm2B = __shfl_xor(cB, 2, 64);
    const float cm3A = __shfl_xor(cm2A, 1, 64);
    const float cm3B = __shfl_xor(cm2B, 1, 64);

    const float t3A = cm2A * cm3A, fullA = cm1A * t3A;
    const float t3B = cm2B * cm3B, fullB = cm1B * t3B;
    zA = (k == 0) ? fullA : (k == 1) ? cA * cm1A : (k == 2) ? cA * t3A : cA * fullA;
    zB = (k == 0) ? fullB : (k == 1) ? cB * cm1B : (k == 2) ? cB * t3B : cB * fullB;
}

__global__ __launch_bounds__(TPB, 4) void qnat_all(const float* __restrict__ x,
                                                   const float* __restrict__ gamma,
                                                   const float* __restrict__ beta,
                                                   float* __restrict__ out,
                                                   float* __restrict__ partials,
                                                   int bsz, int ipb, int nblk) {
    __shared__ float zsh[256][4];
    __shared__ float ps[4][8];
    __shared__ float red[4][8];
    __shared__ float st[8];

    const int t    = threadIdx.x;
    const int lane = t & 63;
    const int w    = t >> 6;                   // wave 0..3
    const int ipw  = ipb >> 2;                 // images per wave (even)
    const int blk0 = blockIdx.x * ipb;
    const int wimg0 = blk0 + w * ipw;

    const bool b0 = (lane & 1) != 0;
    const bool b1 = (lane & 2) != 0;
    const int  k  = lane & 3;
    const int j1 = 64 + lane, j2 = 128 + lane;
    const int m0 = lane % 7, p0 = lane / 42;
    const int m1 = j1 % 7,   p1 = j1 / 42;
    const int m2 = j2 % 7,   p2 = j2 / 42;

    float s1 = 0.f, s2 = 0.f;

    // ---- Phase A ----
    for (int pr = 0; pr < (ipw >> 1); ++pr) {
        const int imgA = wimg0 + pr * 2;
        const int imgB = imgA + 1;
        float zA, zB;
        qnat_pair(x, bsz, imgA, imgB, lane, j1, j2, m0, p0, m1, p1, m2, p2, b0, b1, k, zA, zB);

        if (lane < 8) {
            const int im = (lane < 4) ? imgA : imgB;
            const float zz = (lane < 4) ? zA : zB;
            if (im < bsz) zsh[im - blk0][k] = zz;
        }
        const float zAm = (imgA < bsz) ? zA : 0.f;
        const float zBm = (imgB < bsz) ? zB : 0.f;
        s1 += zAm + zBm;
        s2 += zAm * zAm + zBm * zBm;
    }

    if (lane < 4) { ps[w][lane] = s1; ps[w][4 + lane] = s2; }
    __syncthreads();
    if (t < 8) {
        partials[blockIdx.x * 8 + t] = (ps[0][t] + ps[1][t]) + (ps[2][t] + ps[3][t]);
    }

    cg::this_grid().sync();

    // ---- Phase B: every block redundantly reduces the partials table ----
    {
        float acc[8] = {0.f,0.f,0.f,0.f,0.f,0.f,0.f,0.f};
        for (int r = t; r < nblk; r += TPB) {
            const float4 a = *reinterpret_cast<const float4*>(partials + r * 8);
            const float4 b = *reinterpret_cast<const float4*>(partials + r * 8 + 4);
            acc[0] += a.x; acc[1] += a.y; acc[2] += a.z; acc[3] += a.w;
            acc[4] += b.x; acc[5] += b.y; acc[6] += b.z; acc[7] += b.w;
        }
        #pragma unroll
        for (int off = 1; off < 64; off <<= 1) {
            #pragma unroll
            for (int kk = 0; kk < 8; ++kk) acc[kk] += __shfl_xor(acc[kk], off, 64);
        }
        if (lane == 0) {
            #pragma unroll
            for (int kk = 0; kk < 8; ++kk) red[w][kk] = acc[kk];
        }
        __syncthreads();
        if (t < 8) st[t] = (red[0][t] + red[1][t]) + (red[2][t] + red[3][t]);
        __syncthreads();
        if (t < 4) {
            const double invB = 1.0 / (double)bsz;
            const double m   = (double)st[t] * invB;
            const double var = (double)st[4 + t] * invB - m * m;
            st[t]     = (float)m;
            st[4 + t] = gamma[t] * rsqrtf((float)var + EPS);
        }
        __syncthreads();
    }

    // ---- Phase C: normalize from LDS, write out ----
    for (int i = t; i < ipb; i += TPB) {
        const int img = blk0 + i;
        if (img < bsz) {
            const float4 zv = *reinterpret_cast<const float4*>(&zsh[i][0]);
            float4 o;
            o.x = (zv.x - st[0]) * st[4] + beta[0];
            o.y = (zv.y - st[1]) * st[5] + beta[1];
            o.z = (zv.z - st[2]) * st[6] + beta[2];
            o.w = (zv.w - st[3]) * st[7] + beta[3];
            *reinterpret_cast<float4*>(out + (size_t)img * 4) = o;
        }
    }
}

// ---------------- fallback: round-7 two-kernel path ----------------

__global__ __launch_bounds__(256) void qnat_k1(const float* __restrict__ x,
                                               float* __restrict__ z_out,
                                               float* __restrict__ partials,
                                               int bsz) {
    const int t    = threadIdx.x;
    const int lane = t & 63;
    const int w    = t >> 6;
    const int img0 = blockIdx.x * 16 + w * 4;

    const bool b0 = (lane & 1) != 0;
    const bool b1 = (lane & 2) != 0;
    const int  k  = lane & 3;
    const int j1 = 64 + lane, j2 = 128 + lane;
    const int m0 = lane % 7, p0 = lane / 42;
    const int m1 = j1 % 7,   p1 = j1 / 42;
    const int m2 = j2 % 7,   p2 = j2 / 42;

    float s1 = 0.f, s2 = 0.f;

    #pragma unroll
    for (int pr = 0; pr < 2; ++pr) {
        const int imgA = img0 + pr * 2;
        const int imgB = imgA + 1;
        float zA, zB;
        qnat_pair(x, bsz, imgA, imgB, lane, j1, j2, m0, p0, m1, p1, m2, p2, b0, b1, k, zA, zB);

        if (lane < 8) {
            const int im = (lane < 4) ? imgA : imgB;
            const float zz = (lane < 4) ? zA : zB;
            if (im < bsz) z_out[(size_t)im * 4 + k] = zz;
        }
        const float zAm = (imgA < bsz) ? zA : 0.f;
        const float zBm = (imgB < bsz) ? zB : 0.f;
        s1 += zAm + zBm;
        s2 += zAm * zAm + zBm * zBm;
    }

    __shared__ float ps[4][8];
    if (lane < 4) { ps[w][lane] = s1; ps[w][4 + lane] = s2; }
    __syncthreads();
    if (t < 8) {
        partials[blockIdx.x * 8 + t] = (ps[0][t] + ps[1][t]) + (ps[2][t] + ps[3][t]);
    }
}

__global__ __launch_bounds__(256) void qnat_k2(const float* __restrict__ z,
                                               const float* __restrict__ partials,
                                               const float* __restrict__ gamma,
                                               const float* __restrict__ beta,
                                               float* __restrict__ out,
                                               int NB, int bsz) {
    __shared__ float red[4][8];
    __shared__ float st[8];
    const int t = threadIdx.x, lane = t & 63, w = t >> 6;

    float acc[8] = {0.f,0.f,0.f,0.f,0.f,0.f,0.f,0.f};
    for (int r = t; r < NB; r += 256) {
        const float4 a = *reinterpret_cast<const float4*>(partials + r * 8);
        const float4 b = *reinterpret_cast<const float4*>(partials + r * 8 + 4);
        acc[0] += a.x; acc[1] += a.y; acc[2] += a.z; acc[3] += a.w;
        acc[4] += b.x; acc[5] += b.y; acc[6] += b.z; acc[7] += b.w;
    }
    #pragma unroll
    for (int off = 1; off < 64; off <<= 1) {
        #pragma unroll
        for (int kk = 0; kk < 8; ++kk) acc[kk] += __shfl_xor(acc[kk], off, 64);
    }
    if (lane == 0) {
        #pragma unroll
        for (int kk = 0; kk < 8; ++kk) red[w][kk] = acc[kk];
    }
    __syncthreads();
    if (t < 8) st[t] = (red[0][t] + red[1][t]) + (red[2][t] + red[3][t]);
    __syncthreads();
    if (t < 4) {
        const double invB = 1.0 / (double)bsz;
        const double m   = (double)st[t] * invB;
        const double var = (double)st[4 + t] * invB - m * m;
        st[t]     = (float)m;
        st[4 + t] = gamma[t] * rsqrtf((float)var + EPS);
    }
    __syncthreads();

    const int img0 = blockIdx.x * 1024 + t;
    #pragma unroll
    for (int i = 0; i < 4; ++i) {
        const int img = img0 + i * 256;
        if (img < bsz) {
            const float4 zv = reinterpret_cast<const float4*>(z)[img];
            float4 o;
            o.x = (zv.x - st[0]) * st[4] + beta[0];
            o.y = (zv.y - st[1]) * st[5] + beta[1];
            o.z = (zv.z - st[2]) * st[6] + beta[2];
            o.w = (zv.w - st[3]) * st[7] + beta[3];
            reinterpret_cast<float4*>(out)[img] = o;
        }
    }
}

extern "C" void kernel_launch(void* const* d_in, const int* in_sizes, int n_in,
                              void* d_out, int out_size, void* d_ws, size_t ws_size,
                              hipStream_t stream) {
    const float* x     = (const float*)d_in[0];
    const float* gamma = (const float*)d_in[1];
    const float* beta  = (const float*)d_in[2];
    float* out = (float*)d_out;

    const int bsz = in_sizes[0] / 784;

    // --- query what actually fits co-resident (host-side, capture-safe) ---
    int numCU = 0, maxB = 0;
    int dev = 0;
    (void)hipGetDevice(&dev);
    (void)hipDeviceGetAttribute(&numCU, hipDeviceAttributeMultiprocessorCount, dev);
    (void)hipOccupancyMaxActiveBlocksPerMultiprocessor(&maxB, (const void*)qnat_all, TPB, 0);

    bool launched = false;
    if (numCU > 0 && maxB > 0) {
        const int maxGrid = maxB * numCU;
        int ipb = (bsz + maxGrid - 1) / maxGrid;
        ipb = (ipb + 7) & ~7;                  // multiple of 8 (ipw even)
        if (ipb <= 256) {                      // zsh capacity
            int grid = (bsz + ipb - 1) / ipb;
            if (grid <= maxGrid) {
                float* partials = (float*)d_ws;
                int nblk = grid;
                void* args[] = { (void*)&x, (void*)&gamma, (void*)&beta, (void*)&out,
                                 (void*)&partials, (void*)&bsz, (void*)&ipb, (void*)&nblk };
                hipError_t e = hipLaunchCooperativeKernel((const void*)qnat_all,
                                                          dim3(grid), dim3(TPB),
                                                          args, 0, stream);
                launched = (e == hipSuccess);
            }
        }
    }

    if (!launched) {
        // round-7 proven two-kernel path
        const int NB  = (bsz + 15) / 16;
        const int NB2 = (bsz + 1023) / 1024;
        float* z        = (float*)d_ws;
        float* partials = (float*)((char*)d_ws + (size_t)bsz * 16);
        qnat_k1<<<NB, 256, 0, stream>>>(x, z, partials, bsz);
        qnat_k2<<<NB2, 256, 0, stream>>>(z, partials, gamma, beta, out, NB, bsz);
    }
}

// Round 10
// 39.526 us; speedup vs baseline: 3.3254x; 3.3254x over previous
//
#include <hip/hip_runtime.h>

#define EPS 1e-5f

// Math: theta_p = mean(x[b,0,6p:6p+6,0:6]); c_p = cos(theta_p);
// CNOT chain (0,1)(1,2)(2,3)(3,0) is a classical XOR map =>
// z0=c1*c2*c3, z1=c0*c1, z2=c0*c1*c2, z3=c0*c1*c2*c3; then batchnorm over B.
//
// k1 mapping: 16 lanes per image, 4 images per wave CONCURRENTLY.
//   lane = g*16 + q  (g = image-in-wave, q = slot lane)
//   Each lane loads float4 slots s = 16r + q, r = 0..10 (s < 168 needed; r=10
//   masked to q<8). One base pointer + immediate offsets r*256B -> 11 loads
//   issued back-to-back (11KB in flight per wave).
//   Slot semantics: s = 7*row + {0:cols0-3 (h4), 1:cols4-5 (h2)}, theta = s/42.
//   One packed shuffle stream reduces all 4 images at once:
//     xor1/xor2 fold a0..a3 -> lane owns theta (lane&3); xor4/xor8 finish the
//     16-lane sum; 1 cos per lane; 3 quad broadcasts -> z products.
//
// ws layout:
//   [0, bsz*16)            float z[bsz][4]
//   [bsz*16, +NB*32)       float partials[NB][8] = {sum[4], sumsq[4]},  NB = ceil(bsz/16)

__global__ __launch_bounds__(256) void qnat_k1(const float* __restrict__ x,
                                               float* __restrict__ z_out,
                                               float* __restrict__ partials,
                                               int bsz) {
    const int t    = threadIdx.x;
    const int lane = t & 63;
    const int w    = t >> 6;            // wave 0..3
    const int q    = lane & 15;         // slot lane within image
    const int g    = lane >> 4;         // image 0..3 within wave
    const int img  = blockIdx.x * 16 + w * 4 + g;
    const int last = bsz - 1;
    const int imc  = (img < last) ? img : last;     // clamped (safe address)
    const float* base = x + (size_t)imc * 784 + q * 4;

    // ---- 11 loads, one burst, immediate offsets ----
    float4 v[11];
    #pragma unroll
    for (int r = 0; r < 10; ++r)
        v[r] = *reinterpret_cast<const float4*>(base + r * 64);
    v[10] = make_float4(0.f, 0.f, 0.f, 0.f);
    if (q < 8) v[10] = *reinterpret_cast<const float4*>(base + 640);

    // ---- per-lane masked contributions (r compile-time, q runtime) ----
    float a0 = 0.f, a1 = 0.f, a2 = 0.f, a3 = 0.f;
    #pragma unroll
    for (int r = 0; r < 11; ++r) {
        const int s = r * 16 + q;
        const int m = s % 7;            // 0: cols0-3, 1: cols4-5, else unused
        const int p = s / 42;           // theta index (>=4 -> discarded)
        const float h2 = v[r].x + v[r].y;
        const float h4 = h2 + v[r].z + v[r].w;
        const float c  = (m == 0) ? h4 : ((m == 1) ? h2 : 0.f);
        a0 += (p == 0) ? c : 0.f;
        a1 += (p == 1) ? c : 0.f;
        a2 += (p == 2) ? c : 0.f;
        a3 += (p == 3) ? c : 0.f;
    }

    // ---- packed reduction: one shuffle stream for all 4 images ----
    const bool b0 = (lane & 1) != 0;
    const bool b1 = (lane & 2) != 0;
    const int  k  = lane & 3;

    float r0 = __shfl_xor(b0 ? a0 : a1, 1, 64);
    float u  = (b0 ? a1 : a0) + r0;
    r0 = __shfl_xor(b0 ? a2 : a3, 1, 64);
    float vv = (b0 ? a3 : a2) + r0;
    r0 = __shfl_xor(b1 ? u : vv, 2, 64);
    float ww = (b1 ? vv : u) + r0;      // lane owns theta (lane&3) quad-partial
    ww += __shfl_xor(ww, 4, 64);
    ww += __shfl_xor(ww, 8, 64);        // full 36-elem sum, replicated x4 in group

    const float c   = __cosf(ww * (1.0f / 36.0f));   // c_{lane&3} of image g
    const float cm1 = __shfl_xor(c, 1, 64);
    const float cm2 = __shfl_xor(c, 2, 64);
    const float cm3 = __shfl_xor(cm2, 1, 64);
    const float t3 = cm2 * cm3, full = cm1 * t3;
    const float z = (k == 0) ? full : (k == 1) ? c * cm1
                  : (k == 2) ? c * t3 : c * full;

    const bool valid = (img < bsz);
    // z store: lanes {16g + k} -> 16 consecutive floats per wave (64B line)
    if (valid && q < 4) z_out[(size_t)img * 4 + k] = z;

    // stats: one copy per image (q<4 lanes), then fold image groups
    float sm1 = (valid && q < 4) ? z : 0.f;
    float sm2 = sm1 * z;
    sm1 += __shfl_xor(sm1, 16, 64);
    sm2 += __shfl_xor(sm2, 16, 64);
    sm1 += __shfl_xor(sm1, 32, 64);
    sm2 += __shfl_xor(sm2, 32, 64);     // lanes 0-3 hold per-channel wave totals

    __shared__ float ps[4][8];
    if (lane < 4) { ps[w][lane] = sm1; ps[w][4 + lane] = sm2; }
    __syncthreads();
    if (t < 8) {
        partials[blockIdx.x * 8 + t] = (ps[0][t] + ps[1][t]) + (ps[2][t] + ps[3][t]);
    }
}

// Every block redundantly reduces the partials table (L2/L3-resident, 128 KB),
// computes {mean, scale}, then normalizes its own 1024 images.
__global__ __launch_bounds__(256) void qnat_k2(const float* __restrict__ z,
                                               const float* __restrict__ partials,
                                               const float* __restrict__ gamma,
                                               const float* __restrict__ beta,
                                               float* __restrict__ out,
                                               int NB, int bsz) {
    __shared__ float red[4][8];
    __shared__ float st[8];
    const int t = threadIdx.x, lane = t & 63, w = t >> 6;

    float acc[8] = {0.f,0.f,0.f,0.f,0.f,0.f,0.f,0.f};
    for (int r = t; r < NB; r += 256) {
        const float4 a = *reinterpret_cast<const float4*>(partials + r * 8);
        const float4 b = *reinterpret_cast<const float4*>(partials + r * 8 + 4);
        acc[0] += a.x; acc[1] += a.y; acc[2] += a.z; acc[3] += a.w;
        acc[4] += b.x; acc[5] += b.y; acc[6] += b.z; acc[7] += b.w;
    }
    #pragma unroll
    for (int off = 1; off < 64; off <<= 1) {
        #pragma unroll
        for (int kk = 0; kk < 8; ++kk) acc[kk] += __shfl_xor(acc[kk], off, 64);
    }
    if (lane == 0) {
        #pragma unroll
        for (int kk = 0; kk < 8; ++kk) red[w][kk] = acc[kk];
    }
    __syncthreads();
    if (t < 8) st[t] = (red[0][t] + red[1][t]) + (red[2][t] + red[3][t]);
    __syncthreads();
    if (t < 4) {
        const double invB = 1.0 / (double)bsz;
        const double m   = (double)st[t] * invB;
        const double var = (double)st[4 + t] * invB - m * m;
        st[t]     = (float)m;
        st[4 + t] = gamma[t] * rsqrtf((float)var + EPS);
    }
    __syncthreads();

    const int img0 = blockIdx.x * 1024 + t;
    #pragma unroll
    for (int i = 0; i < 4; ++i) {
        const int img = img0 + i * 256;
        if (img < bsz) {
            const float4 zv = reinterpret_cast<const float4*>(z)[img];
            float4 o;
            o.x = (zv.x - st[0]) * st[4] + beta[0];
            o.y = (zv.y - st[1]) * st[5] + beta[1];
            o.z = (zv.z - st[2]) * st[6] + beta[2];
            o.w = (zv.w - st[3]) * st[7] + beta[3];
            reinterpret_cast<float4*>(out)[img] = o;
        }
    }
}

extern "C" void kernel_launch(void* const* d_in, const int* in_sizes, int n_in,
                              void* d_out, int out_size, void* d_ws, size_t ws_size,
                              hipStream_t stream) {
    const float* x     = (const float*)d_in[0];
    const float* gamma = (const float*)d_in[1];
    const float* beta  = (const float*)d_in[2];
    float* out = (float*)d_out;

    const int bsz = in_sizes[0] / 784;
    const int NB  = (bsz + 15) / 16;
    const int NB2 = (bsz + 1023) / 1024;

    float* z        = (float*)d_ws;
    float* partials = (float*)((char*)d_ws + (size_t)bsz * 16);

    qnat_k1<<<NB, 256, 0, stream>>>(x, z, partials, bsz);
    qnat_k2<<<NB2, 256, 0, stream>>>(z, partials, gamma, beta, out, NB, bsz);
}